// Round 7
// baseline (24.298 us; speedup 1.0000x reference)
//
#include <hip/hip_runtime.h>
#include <hip/hip_bf16.h>
#include <math.h>

// Problem constants (from reference setup_inputs)
#define BATCH   512          // bs * n_vars
#define KP      3            // k_positive
#define KN      16           // k_negative
#define KTOT    (KP + KN)    // 19
#define PD      8192         // P * D
#define INV_T   50.0f        // 1 / temperature

#define SLICE   32                 // floats per block d-slice (128 B)
#define NBLK    (PD / SLICE)       // 256 blocks (1 per CU)
#define THREADS 512                // 8 waves; 64 samples per pass
#define PASSES  (BATCH / (THREADS / 8))   // 8

typedef float f32x4 __attribute__((ext_vector_type(4)));

// --- kernel 1: per-sample softmax weights -> d_ws (float[512][19])
__global__ __launch_bounds__(256)
void softmax_w_kernel(const float* __restrict__ sim, float* __restrict__ w_out) {
    const int b = blockIdx.x * blockDim.x + threadIdx.x;
    if (b >= BATCH) return;
    float v[KTOT];
    float m = -INFINITY;
    #pragma unroll
    for (int k = 0; k < KTOT; ++k) {
        v[k] = sim[b * KTOT + k] * INV_T;
        m = fmaxf(m, v[k]);
    }
    float s = 0.0f;
    #pragma unroll
    for (int k = 0; k < KTOT; ++k) {
        v[k] = __expf(v[k] - m);
        s += v[k];
    }
    const float inv = 1.0f / s;
    #pragma unroll
    for (int k = 0; k < KTOT; ++k) w_out[b * KTOT + k] = v[k] * inv;
}

// --- kernel 2: each block owns a 128B d-slice; stage all 512 source-row
// slices in LDS once (negatives panel read exactly once from HBM), then
// compute that slice for all 512 samples from LDS + streamed positives.
__global__ __launch_bounds__(THREADS)
void agg_rebuild_kernel(const float* __restrict__ p_enc,
                        const int*   __restrict__ neg_idx,
                        const float* __restrict__ w,
                        float*       __restrict__ out) {
    const int j   = blockIdx.x;        // d-slice index, 0..255
    const int tid = threadIdx.x;

    __shared__ float lds[BATCH][SLICE];  // 64 KB: X[:512, j*32:(j+1)*32]

    // stage: f32x4-linear index i = row*8 + part; coalesced 8 rows x 128B/wave
    #pragma unroll
    for (int i = tid; i < BATCH * (SLICE / 4); i += THREADS) {
        const int row  = i >> 3;
        const int part = i & 7;
        reinterpret_cast<f32x4*>(&lds[0][0])[i] =
            *reinterpret_cast<const f32x4*>(
                p_enc + (size_t)row * PD + j * SLICE + part * 4);
    }
    __syncthreads();

    const int part = tid & 7;          // which f32x4 of the slice
    const int sl   = tid >> 3;         // 0..63: sample-lane within pass
    const int dcol = j * SLICE + part * 4;

    for (int p = 0; p < PASSES; ++p) {
        const int s = p * (THREADS / 8) + sl;      // sample index
        const float* wrow = w + s * KTOT;
        const int*   irow = neg_idx + s * KN;

        f32x4 acc = {0.f, 0.f, 0.f, 0.f};

        // negatives from LDS (bank-clean: 2 rows per 16-lane quarter)
        #pragma unroll
        for (int k = 0; k < KN; ++k) {
            const int r = irow[k];
            const f32x4 v = *reinterpret_cast<const f32x4*>(&lds[r][part * 4]);
            acc += wrow[KP + k] * v;
        }
        // positives streamed from HBM (each byte read exactly once chip-wide)
        #pragma unroll
        for (int k = 0; k < KP; ++k) {
            const f32x4 v = *reinterpret_cast<const f32x4*>(
                p_enc + (size_t)(BATCH + s * KP + k) * PD + dcol);
            acc += wrow[k] * v;
        }

        *reinterpret_cast<f32x4*>(out + (size_t)s * PD + dcol) = acc;
    }
}

extern "C" void kernel_launch(void* const* d_in, const int* in_sizes, int n_in,
                              void* d_out, int out_size, void* d_ws, size_t ws_size,
                              hipStream_t stream) {
    const float* sim     = (const float*)d_in[0];   // [B, 19]
    const float* p_enc   = (const float*)d_in[1];   // [B*(1+KP), P, D]
    const int*   neg_idx = (const int*)d_in[2];     // [B, KN]
    float*       out     = (float*)d_out;           // [B, P, D]
    float*       w_ws    = (float*)d_ws;            // [B, 19] scratch

    softmax_w_kernel<<<dim3(2), dim3(256), 0, stream>>>(sim, w_ws);
    agg_rebuild_kernel<<<dim3(NBLK), dim3(THREADS), 0, stream>>>(
        p_enc, neg_idx, w_ws, out);
}